// Round 5
// baseline (1956.636 us; speedup 1.0000x reference)
//
#include <hip/hip_runtime.h>

#define Bsz  256
#define Tlen 2048
#define Hdim 128
#define HP   160   // padded h buffer: unit u stored at u + (u>>4)*4 (max 155)
#define NTHR 1024

typedef float vf2 __attribute__((ext_vector_type(2)));

__device__ __forceinline__ float sigmoidf_(float v) { return 1.0f / (1.0f + __expf(-v)); }
__device__ __forceinline__ float tanhf_(float v)    { return 1.0f - 2.0f / (__expf(2.0f * v) + 1.0f); }

// Keep a value pinned in a VGPR (non-rematerializable, cannot be sunk into loop)
__device__ __forceinline__ void pin2(vf2& v) { asm volatile("" : "+v"(v)); }

// DPP butterfly add over groups of 8 consecutive lanes — pure VALU pipe.
template <int CTRL>
__device__ __forceinline__ float dpp_add(float v) {
    int t = __builtin_amdgcn_update_dpp(0, __float_as_int(v), CTRL, 0xf, 0xf, true);
    return v + __int_as_float(t);
}
// 0xB1 = quad_perm xor1, 0x4E = quad_perm xor2,
// 0x141 = row_half_mirror (pairs each quad with the other quad of its own
// 8-lane group). Full 8-lane allreduce, zero DS ops.
__device__ __forceinline__ float red8(float v) {
    v = dpp_add<0xB1>(v);
    v = dpp_add<0x4E>(v);
    v = dpp_add<0x141>(v);
    return v;
}

// grid = 256 blocks (one batch row per block), block = 1024 threads (16 waves).
// thread t: kc = t & 7 -> k-chunk [kc*16, kc*16+16)
//           u  = t >> 3 -> hidden unit 0..127; owns Whh rows {u, u+128, u+256}
//           over its k-chunk: 48 weights + 16 Wfc = 64 VGPRs, register-resident
//           (total live ~105 < the 128-VGPR budget forced by 1024-thread blocks).
// After the 8-lane DPP allreduce every lane of a group holds the full gate dots
// and xp, so gate math runs unpredicated; only the h write is lane-kc==0.
__global__ __launch_bounds__(NTHR)
__attribute__((amdgpu_waves_per_eu(4, 4)))
void rnn_imp_kernel(const float* __restrict__ x,     // [B, T] (I=1)
                    const float* __restrict__ Wih,   // [384]
                    const float* __restrict__ Whh,   // [384, 128]
                    const float* __restrict__ bih,   // [384]
                    const float* __restrict__ bhh,   // [384]
                    const float* __restrict__ Wfc,   // [128]
                    const float* __restrict__ bfc,   // [1]
                    float* __restrict__ out_newin,   // [T, B]
                    float* __restrict__ out_pred)    // [B, T-1]
{
    __shared__ __align__(16) float x_s[Tlen + 4];
    __shared__ __align__(16) float h_s[2][HP];

    const int tid = threadIdx.x;
    const int b   = blockIdx.x;
    const int kc  = tid & 7;
    const int u   = tid >> 3;

    // stage x row (coalesced) and zero h buffer 0
    for (int i = tid; i < Tlen; i += NTHR) x_s[i] = x[b * Tlen + i];
    if (tid < HP) h_s[0][tid] = 0.0f;

    // Whh strip: rows {u, u+128, u+256} (r,z,n), 16 k each -> 48 floats
    vf2 w2[3][8];
#pragma unroll
    for (int g = 0; g < 3; ++g) {
        const float4* wp = (const float4*)(Whh + (g * Hdim + u) * Hdim + kc * 16);
#pragma unroll
        for (int j = 0; j < 4; ++j) {
            float4 v = wp[j];
            w2[g][2 * j + 0] = vf2{v.x, v.y};
            w2[g][2 * j + 1] = vf2{v.z, v.w};
        }
    }
    // Wfc chunk for the (redundant-per-group) imputation dot
    vf2 wfc2[8];
    {
        const float4* fp = (const float4*)(Wfc + kc * 16);
#pragma unroll
        for (int j = 0; j < 4; ++j) {
            float4 v = fp[j];
            wfc2[2 * j + 0] = vf2{v.x, v.y};
            wfc2[2 * j + 1] = vf2{v.z, v.w};
        }
    }
#pragma unroll
    for (int g = 0; g < 3; ++g)
#pragma unroll
        for (int i = 0; i < 8; ++i) pin2(w2[g][i]);
#pragma unroll
    for (int i = 0; i < 8; ++i) pin2(wfc2[i]);

    // per-unit gate constants (identical across the 8 lanes of a group)
    const float wih_r = Wih[u],        wih_z = Wih[u + 128],  wih_n = Wih[u + 256];
    const float bih_r = bih[u],        bih_z = bih[u + 128],  bih_n = bih[u + 256];
    const float bhh_r = bhh[u],        bhh_z = bhh[u + 128],  bhh_n = bhh[u + 256];
    const float bfc0  = bfc[0];
    float h_old = 0.0f;

    const int rbase = kc * 20;                      // padded chunk base (words)
    const int pu    = u + (u >> 4) * 4;             // padded write position

    __syncthreads();

#pragma unroll 1
    for (int t = 0; t < Tlen; ++t) {
        const float* hb = h_s[t & 1];
        float*       hw = h_s[(t + 1) & 1];
        float xt = x_s[t];

        // h chunk: 4x ds_read_b128; 8 distinct bases cover all 32 banks once,
        // 8-fold same-address broadcast across groups (conflict-free)
        const float4* hp = (const float4*)(hb + rbase);
        float4 q0 = hp[0], q1 = hp[1], q2 = hp[2], q3 = hp[3];
        vf2 hv[8] = { vf2{q0.x, q0.y}, vf2{q0.z, q0.w},
                      vf2{q1.x, q1.y}, vf2{q1.z, q1.w},
                      vf2{q2.x, q2.y}, vf2{q2.z, q2.w},
                      vf2{q3.x, q3.y}, vf2{q3.z, q3.w} };

        vf2 a0 = vf2{0.f, 0.f}, a1 = vf2{0.f, 0.f},
            a2v = vf2{0.f, 0.f}, xp2 = vf2{0.f, 0.f};
#pragma unroll
        for (int i = 0; i < 8; ++i) {
            vf2 h2 = hv[i];
            a0  += w2[0][i] * h2;
            a1  += w2[1][i] * h2;
            a2v += w2[2][i] * h2;
            xp2 += wfc2[i] * h2;
        }
        // 8-lane DPP butterfly; every lane ends with the full sums
        float ar = red8(a0.x + a0.y);
        float az = red8(a1.x + a1.y);
        float an = red8(a2v.x + a2v.y);
        float xp = red8(xp2.x + xp2.y);

        float xh  = xp + bfc0;
        float cur = ((xt == 128.0f) && (t != 0)) ? xh : xt;

        float r  = sigmoidf_(wih_r * cur + bih_r + ar + bhh_r);
        float z  = sigmoidf_(wih_z * cur + bih_z + az + bhh_z);
        float n  = tanhf_(wih_n * cur + bih_n + r * (an + bhh_n));
        float hn = (1.0f - z) * n + z * h_old;
        h_old = hn;

        if (kc == 0) hw[pu] = hn;
        if (tid == 0) {
            out_newin[t * Bsz + b] = cur;
            if (t != 0) out_pred[b * (Tlen - 1) + (t - 1)] = xh;
        }
        __syncthreads();
    }
}

extern "C" void kernel_launch(void* const* d_in, const int* in_sizes, int n_in,
                              void* d_out, int out_size, void* d_ws, size_t ws_size,
                              hipStream_t stream) {
    const float* x   = (const float*)d_in[0];
    const float* Wih = (const float*)d_in[1];
    const float* Whh = (const float*)d_in[2];
    const float* bih = (const float*)d_in[3];
    const float* bhh = (const float*)d_in[4];
    const float* Wfc = (const float*)d_in[5];
    const float* bfc = (const float*)d_in[6];

    float* out_newin = (float*)d_out;                 // [T*B] = 524288
    float* out_pred  = out_newin + Tlen * Bsz;        // [B*(T-1)] = 524032

    rnn_imp_kernel<<<Bsz, NTHR, 0, stream>>>(x, Wih, Whh, bih, bhh, Wfc, bfc,
                                             out_newin, out_pred);
}

// Round 7
// 1781.254 us; speedup vs baseline: 1.0985x; 1.0985x over previous
//
#include <hip/hip_runtime.h>

#define Bsz  256
#define Tlen 2048
#define Hdim 128
#define HP   160   // padded h buffer: unit u stored at u + (u>>4)*4 (max 155)

typedef float vf2 __attribute__((ext_vector_type(2)));

__device__ __forceinline__ float sigmoidf_(float v) { return 1.0f / (1.0f + __expf(-v)); }
__device__ __forceinline__ float tanhf_(float v)    { return 1.0f - 2.0f / (__expf(2.0f * v) + 1.0f); }

// Pin an SSA value into a VGPR pair: opaque to remat/sinking.
__device__ __forceinline__ void pin2(vf2& v) { asm volatile("" : "+v"(v)); }

// DPP butterfly add over groups of 8 consecutive lanes — pure VALU pipe.
template <int CTRL>
__device__ __forceinline__ float dpp_add(float v) {
    int t = __builtin_amdgcn_update_dpp(0, __float_as_int(v), CTRL, 0xf, 0xf, true);
    return v + __int_as_float(t);
}
// 0xB1 quad_perm xor1, 0x4E quad_perm xor2, 0x141 row_half_mirror
// (pairs each quad with the other quad of its own 8-lane group).
// Full 8-lane allreduce, zero DS ops. HW-verified in R4 (passed, absmax 4.9e-4).
__device__ __forceinline__ float red8(float v) {
    v = dpp_add<0xB1>(v);
    v = dpp_add<0x4E>(v);
    v = dpp_add<0x141>(v);
    return v;
}

// --- named-scalar weight strips (NO arrays -> nothing can land in scratch) ---
#define DECL8(p) vf2 p##0, p##1, p##2, p##3, p##4, p##5, p##6, p##7
#define LOAD8(p, ptr) do {                                   \
    const float4* _q = (const float4*)(ptr);                 \
    float4 _a = _q[0], _b = _q[1], _c = _q[2], _d = _q[3];   \
    p##0 = vf2{_a.x, _a.y}; p##1 = vf2{_a.z, _a.w};          \
    p##2 = vf2{_b.x, _b.y}; p##3 = vf2{_b.z, _b.w};          \
    p##4 = vf2{_c.x, _c.y}; p##5 = vf2{_c.z, _c.w};          \
    p##6 = vf2{_d.x, _d.y}; p##7 = vf2{_d.z, _d.w}; } while (0)
#define PIN8(p) do { pin2(p##0); pin2(p##1); pin2(p##2); pin2(p##3); \
                     pin2(p##4); pin2(p##5); pin2(p##6); pin2(p##7); } while (0)
#define FMA8(acc, p) do {                                    \
    acc += p##0 * h0; acc += p##1 * h1; acc += p##2 * h2;    \
    acc += p##3 * h3; acc += p##4 * h4; acc += p##5 * h5;    \
    acc += p##6 * h6; acc += p##7 * h7; } while (0)

// grid = 256 blocks (one batch row per block), block = 512 threads (8 waves).
// thread t: kc = t & 7 -> k-chunk [kc*16, kc*16+16)
//           rg = t >> 3 -> unit pair u0 = 2*rg, u0+1; owns Whh rows
//           {u0,u0+1} x {r,z,n} over its k-chunk: 96 + 16 Wfc floats, all in
//           named vf2 scalars (112 VGPRs of weights; budget 256 via waves_per_eu 2).
__global__ __launch_bounds__(512)
__attribute__((amdgpu_waves_per_eu(2, 2)))
void rnn_imp_kernel(const float* __restrict__ x,     // [B, T] (I=1)
                    const float* __restrict__ Wih,   // [384]
                    const float* __restrict__ Whh,   // [384, 128]
                    const float* __restrict__ bih,   // [384]
                    const float* __restrict__ bhh,   // [384]
                    const float* __restrict__ Wfc,   // [128]
                    const float* __restrict__ bfc,   // [1]
                    float* __restrict__ out_newin,   // [T, B]
                    float* __restrict__ out_pred)    // [B, T-1]
{
    __shared__ __align__(16) float x_s[Tlen + 4];
    __shared__ __align__(16) float h_s[2][HP];

    const int tid = threadIdx.x;
    const int b   = blockIdx.x;
    const int kc  = tid & 7;
    const int rg  = tid >> 3;
    const int u0  = rg * 2;

    // stage x row (coalesced) and zero h buffer 0
    for (int i = tid; i < Tlen; i += 512) x_s[i] = x[b * Tlen + i];
    if (tid < HP) h_s[0][tid] = 0.0f;

    // weight strips as named scalars
    DECL8(wr0); DECL8(wr1); DECL8(wz0); DECL8(wz1); DECL8(wn0); DECL8(wn1); DECL8(wf);
    LOAD8(wr0, Whh + (0 * Hdim + u0 + 0) * Hdim + kc * 16);
    LOAD8(wr1, Whh + (0 * Hdim + u0 + 1) * Hdim + kc * 16);
    LOAD8(wz0, Whh + (1 * Hdim + u0 + 0) * Hdim + kc * 16);
    LOAD8(wz1, Whh + (1 * Hdim + u0 + 1) * Hdim + kc * 16);
    LOAD8(wn0, Whh + (2 * Hdim + u0 + 0) * Hdim + kc * 16);
    LOAD8(wn1, Whh + (2 * Hdim + u0 + 1) * Hdim + kc * 16);
    LOAD8(wf,  Wfc + kc * 16);
    PIN8(wr0); PIN8(wr1); PIN8(wz0); PIN8(wz1); PIN8(wn0); PIN8(wn1); PIN8(wf);

    // per-unit gate constants (identical across the 8 lanes of a group)
    const float wih_r0 = Wih[u0],     wih_r1 = Wih[u0 + 1];
    const float wih_z0 = Wih[u0+128], wih_z1 = Wih[u0 + 129];
    const float wih_n0 = Wih[u0+256], wih_n1 = Wih[u0 + 257];
    const float bb_r0 = bih[u0]     + bhh[u0],       bb_r1 = bih[u0+1]   + bhh[u0+1];
    const float bb_z0 = bih[u0+128] + bhh[u0+128],   bb_z1 = bih[u0+129] + bhh[u0+129];
    const float bi_n0 = bih[u0+256], bi_n1 = bih[u0 + 257];
    const float bh_n0 = bhh[u0+256], bh_n1 = bhh[u0 + 257];
    const float bfc0  = bfc[0];
    float h_old0 = 0.0f, h_old1 = 0.0f;

    const int rbase = kc * 20;                      // padded chunk base (words)
    const int pu0   = u0 + (u0 >> 4) * 4;           // padded write position (even)

    __syncthreads();

#pragma unroll 1
    for (int t = 0; t < Tlen; ++t) {
        const float* hb = h_s[t & 1];
        float*       hw = h_s[(t + 1) & 1];
        float xt = x_s[t];

        // h chunk: 4x ds_read_b128; 8 distinct bases (banks 0,20,8,28,16,4,24,12)
        const float4* hp = (const float4*)(hb + rbase);
        float4 q0 = hp[0], q1 = hp[1], q2 = hp[2], q3 = hp[3];
        vf2 h0 = vf2{q0.x, q0.y}, h1 = vf2{q0.z, q0.w},
            h2 = vf2{q1.x, q1.y}, h3 = vf2{q1.z, q1.w},
            h4 = vf2{q2.x, q2.y}, h5 = vf2{q2.z, q2.w},
            h6 = vf2{q3.x, q3.y}, h7 = vf2{q3.z, q3.w};

        vf2 ar0 = vf2{0.f,0.f}, ar1 = vf2{0.f,0.f},
            az0 = vf2{0.f,0.f}, az1 = vf2{0.f,0.f},
            an0 = vf2{0.f,0.f}, an1 = vf2{0.f,0.f},
            axp = vf2{0.f,0.f};
        FMA8(ar0, wr0); FMA8(ar1, wr1);
        FMA8(az0, wz0); FMA8(az1, wz1);
        FMA8(an0, wn0); FMA8(an1, wn1);
        FMA8(axp, wf);

        // 8-lane DPP butterfly; every lane ends with the full sums
        float gr0 = red8(ar0.x + ar0.y);
        float gr1 = red8(ar1.x + ar1.y);
        float gz0 = red8(az0.x + az0.y);
        float gz1 = red8(az1.x + az1.y);
        float gn0 = red8(an0.x + an0.y);
        float gn1 = red8(an1.x + an1.y);
        float xp  = red8(axp.x + axp.y);

        float xh  = xp + bfc0;
        float cur = ((xt == 128.0f) && (t != 0)) ? xh : xt;

        float r0 = sigmoidf_(wih_r0 * cur + bb_r0 + gr0);
        float z0 = sigmoidf_(wih_z0 * cur + bb_z0 + gz0);
        float n0 = tanhf_(wih_n0 * cur + bi_n0 + r0 * (gn0 + bh_n0));
        float hn0 = (1.0f - z0) * n0 + z0 * h_old0;

        float r1 = sigmoidf_(wih_r1 * cur + bb_r1 + gr1);
        float z1 = sigmoidf_(wih_z1 * cur + bb_z1 + gz1);
        float n1 = tanhf_(wih_n1 * cur + bi_n1 + r1 * (gn1 + bh_n1));
        float hn1 = (1.0f - z1) * n1 + z1 * h_old1;

        h_old0 = hn0; h_old1 = hn1;

        if (kc == 0) {
            *(float2*)(hw + pu0) = make_float2(hn0, hn1);
        }
        if (tid == 0) {
            out_newin[t * Bsz + b] = cur;
            if (t != 0) out_pred[b * (Tlen - 1) + (t - 1)] = xh;
        }
        __syncthreads();
    }
}

extern "C" void kernel_launch(void* const* d_in, const int* in_sizes, int n_in,
                              void* d_out, int out_size, void* d_ws, size_t ws_size,
                              hipStream_t stream) {
    const float* x   = (const float*)d_in[0];
    const float* Wih = (const float*)d_in[1];
    const float* Whh = (const float*)d_in[2];
    const float* bih = (const float*)d_in[3];
    const float* bhh = (const float*)d_in[4];
    const float* Wfc = (const float*)d_in[5];
    const float* bfc = (const float*)d_in[6];

    float* out_newin = (float*)d_out;                 // [T*B] = 524288
    float* out_pred  = out_newin + Tlen * Bsz;        // [B*(T-1)] = 524032

    rnn_imp_kernel<<<Bsz, 512, 0, stream>>>(x, Wih, Whh, bih, bhh, Wfc, bfc,
                                            out_newin, out_pred);
}

// Round 10
// 1753.784 us; speedup vs baseline: 1.1157x; 1.0157x over previous
//
#include <hip/hip_runtime.h>

#define Bsz  256
#define Tlen 2048
#define Hdim 128

typedef __fp16 hf2 __attribute__((ext_vector_type(2)));

__device__ __forceinline__ float sigmoidf_(float v) { return 1.0f / (1.0f + __expf(-v)); }
__device__ __forceinline__ float tanhf_(float v)    { return 1.0f - 2.0f / (__expf(2.0f * v) + 1.0f); }

// Pin a packed-f16 pair into a VGPR (opaque to remat/sinking).
__device__ __forceinline__ void pinh(hf2& v) { asm volatile("" : "+v"(v)); }

// DPP butterfly add over groups of 8 consecutive lanes — pure VALU pipe.
template <int CTRL>
__device__ __forceinline__ float dpp_add(float v) {
    int t = __builtin_amdgcn_update_dpp(0, __float_as_int(v), CTRL, 0xf, 0xf, true);
    return v + __int_as_float(t);
}
// 0xB1 quad_perm xor1, 0x4E quad_perm xor2, 0x141 row_half_mirror.
// Full 8-lane allreduce, zero DS ops. HW-verified R4/R7 (absmax 4.9e-4).
__device__ __forceinline__ float red8(float v) {
    v = dpp_add<0xB1>(v);
    v = dpp_add<0x4E>(v);
    v = dpp_add<0x141>(v);
    return v;
}

// --- named packed-f16 weight strips (16 f32 -> 8 packed VGPRs each) ---
#define DECL8(p) hf2 p##0, p##1, p##2, p##3, p##4, p##5, p##6, p##7
#define LOAD8H(p, ptr) do {                                          \
    const float4* _q = (const float4*)(ptr);                         \
    float4 _a = _q[0], _b = _q[1], _c = _q[2], _d = _q[3];           \
    p##0 = __builtin_amdgcn_cvt_pkrtz(_a.x, _a.y);                   \
    p##1 = __builtin_amdgcn_cvt_pkrtz(_a.z, _a.w);                   \
    p##2 = __builtin_amdgcn_cvt_pkrtz(_b.x, _b.y);                   \
    p##3 = __builtin_amdgcn_cvt_pkrtz(_b.z, _b.w);                   \
    p##4 = __builtin_amdgcn_cvt_pkrtz(_c.x, _c.y);                   \
    p##5 = __builtin_amdgcn_cvt_pkrtz(_c.z, _c.w);                   \
    p##6 = __builtin_amdgcn_cvt_pkrtz(_d.x, _d.y);                   \
    p##7 = __builtin_amdgcn_cvt_pkrtz(_d.z, _d.w); } while (0)
#define PINH8(p) do { pinh(p##0); pinh(p##1); pinh(p##2); pinh(p##3); \
                      pinh(p##4); pinh(p##5); pinh(p##6); pinh(p##7); } while (0)
// 8 chained v_dot2_f32_f16: acc += sum_j p_j . h_j  (f32 accumulate)
#define DOT8(acc, p) do {                                            \
    acc = __builtin_amdgcn_fdot2(p##0, h0, acc, false);              \
    acc = __builtin_amdgcn_fdot2(p##1, h1, acc, false);              \
    acc = __builtin_amdgcn_fdot2(p##2, h2, acc, false);              \
    acc = __builtin_amdgcn_fdot2(p##3, h3, acc, false);              \
    acc = __builtin_amdgcn_fdot2(p##4, h4, acc, false);              \
    acc = __builtin_amdgcn_fdot2(p##5, h5, acc, false);              \
    acc = __builtin_amdgcn_fdot2(p##6, h6, acc, false);              \
    acc = __builtin_amdgcn_fdot2(p##7, h7, acc, false); } while (0)

// grid = 256 blocks (one batch row per block), block = 512 threads (8 waves).
// thread t: kc = t & 7 -> k-chunk [kc*16, kc*16+16)
//           rg = t >> 3 -> unit pair u0 = 2*rg, u0+1; owns Whh rows
//           {u0,u0+1} x {r,z,n} over its k-chunk as packed f16 (48 VGPRs)
//           + Wfc chunk (8 VGPRs). Total live ~100 VGPRs -> fits the
//           allocator's natural budget; no AGPR spill/copy churn (R7/R8 lesson:
//           VOP3P can't read AGPRs, AGPR spills cost ~112 v_accvgpr_read/step).
// h lives in LDS as packed f16, chunk kc at hf2 index kc*12 (48B stride:
// 16B-aligned, banks kc*12%32 = {0,12,24,4,16,28,8,20} all distinct).
__global__ __launch_bounds__(512)
void rnn_imp_kernel(const float* __restrict__ x,     // [B, T] (I=1)
                    const float* __restrict__ Wih,   // [384]
                    const float* __restrict__ Whh,   // [384, 128]
                    const float* __restrict__ bih,   // [384]
                    const float* __restrict__ bhh,   // [384]
                    const float* __restrict__ Wfc,   // [128]
                    const float* __restrict__ bfc,   // [1]
                    float* __restrict__ out_newin,   // [T, B]
                    float* __restrict__ out_pred)    // [B, T-1]
{
    __shared__ __align__(16) float x_s[Tlen + 4];
    __shared__ __align__(16) hf2  h16_s[2][96];      // 8 chunks x (8 data + 4 pad)

    const int tid = threadIdx.x;
    const int b   = blockIdx.x;
    const int kc  = tid & 7;
    const int rg  = tid >> 3;
    const int u0  = rg * 2;

    // stage x row (coalesced) and zero h buffer 0
    for (int i = tid; i < Tlen; i += 512) x_s[i] = x[b * Tlen + i];
    if (tid < 96) h16_s[0][tid] = hf2{(__fp16)0, (__fp16)0};

    // weight strips -> packed f16 named scalars
    DECL8(wr0); DECL8(wr1); DECL8(wz0); DECL8(wz1); DECL8(wn0); DECL8(wn1); DECL8(wf);
    LOAD8H(wr0, Whh + (0 * Hdim + u0 + 0) * Hdim + kc * 16);
    LOAD8H(wr1, Whh + (0 * Hdim + u0 + 1) * Hdim + kc * 16);
    LOAD8H(wz0, Whh + (1 * Hdim + u0 + 0) * Hdim + kc * 16);
    LOAD8H(wz1, Whh + (1 * Hdim + u0 + 1) * Hdim + kc * 16);
    LOAD8H(wn0, Whh + (2 * Hdim + u0 + 0) * Hdim + kc * 16);
    LOAD8H(wn1, Whh + (2 * Hdim + u0 + 1) * Hdim + kc * 16);
    LOAD8H(wf,  Wfc + kc * 16);
    PINH8(wr0); PINH8(wr1); PINH8(wz0); PINH8(wz1); PINH8(wn0); PINH8(wn1); PINH8(wf);

    // per-unit gate constants (identical across the 8 lanes of a group)
    const float wih_r0 = Wih[u0],     wih_r1 = Wih[u0 + 1];
    const float wih_z0 = Wih[u0+128], wih_z1 = Wih[u0 + 129];
    const float wih_n0 = Wih[u0+256], wih_n1 = Wih[u0 + 257];
    const float bb_r0 = bih[u0]     + bhh[u0],       bb_r1 = bih[u0+1]   + bhh[u0+1];
    const float bb_z0 = bih[u0+128] + bhh[u0+128],   bb_z1 = bih[u0+129] + bhh[u0+129];
    const float bi_n0 = bih[u0+256], bi_n1 = bih[u0 + 257];
    const float bh_n0 = bhh[u0+256], bh_n1 = bhh[u0 + 257];
    const float bfc0  = bfc[0];
    float h_old0 = 0.0f, h_old1 = 0.0f;

    const int rbase = kc * 12;                              // hf2 chunk base
    const int pw    = (u0 >> 4) * 12 + ((u0 >> 1) & 7);     // hf2 write slot

    __syncthreads();

#pragma unroll 1
    for (int t = 0; t < Tlen; ++t) {
        const hf2* hb = h16_s[t & 1];
        hf2*       hw = h16_s[(t + 1) & 1];
        float xt = x_s[t];

        // h chunk: 2x ds_read_b128 of packed f16 (16 values)
        const float4* hp = (const float4*)(hb + rbase);
        float4 qa = hp[0], qb = hp[1];
        hf2 h0 = __builtin_bit_cast(hf2, qa.x), h1 = __builtin_bit_cast(hf2, qa.y),
            h2 = __builtin_bit_cast(hf2, qa.z), h3 = __builtin_bit_cast(hf2, qa.w),
            h4 = __builtin_bit_cast(hf2, qb.x), h5 = __builtin_bit_cast(hf2, qb.y),
            h6 = __builtin_bit_cast(hf2, qb.z), h7 = __builtin_bit_cast(hf2, qb.w);

        float ar0 = 0.f, ar1 = 0.f, az0 = 0.f, az1 = 0.f,
              an0 = 0.f, an1 = 0.f, axp = 0.f;
        DOT8(axp, wf);                  // xp first: xh feeds the gate chain
        DOT8(ar0, wr0); DOT8(ar1, wr1);
        DOT8(az0, wz0); DOT8(az1, wz1);
        DOT8(an0, wn0); DOT8(an1, wn1);

        // 8-lane DPP butterfly; every lane ends with the full sums
        float xp  = red8(axp);
        float gr0 = red8(ar0);
        float gr1 = red8(ar1);
        float gz0 = red8(az0);
        float gz1 = red8(az1);
        float gn0 = red8(an0);
        float gn1 = red8(an1);

        float xh  = xp + bfc0;
        float cur = ((xt == 128.0f) && (t != 0)) ? xh : xt;

        float r0 = sigmoidf_(wih_r0 * cur + bb_r0 + gr0);
        float z0 = sigmoidf_(wih_z0 * cur + bb_z0 + gz0);
        float n0 = tanhf_(wih_n0 * cur + bi_n0 + r0 * (gn0 + bh_n0));
        float hn0 = (1.0f - z0) * n0 + z0 * h_old0;

        float r1 = sigmoidf_(wih_r1 * cur + bb_r1 + gr1);
        float z1 = sigmoidf_(wih_z1 * cur + bb_z1 + gz1);
        float n1 = tanhf_(wih_n1 * cur + bi_n1 + r1 * (gn1 + bh_n1));
        float hn1 = (1.0f - z1) * n1 + z1 * h_old1;

        h_old0 = hn0; h_old1 = hn1;

        if (kc == 0) {
            hw[pw] = __builtin_amdgcn_cvt_pkrtz(hn0, hn1);
        }
        if (tid == 0) {
            out_newin[t * Bsz + b] = cur;
            if (t != 0) out_pred[b * (Tlen - 1) + (t - 1)] = xh;
        }
        __syncthreads();
    }
}

extern "C" void kernel_launch(void* const* d_in, const int* in_sizes, int n_in,
                              void* d_out, int out_size, void* d_ws, size_t ws_size,
                              hipStream_t stream) {
    const float* x   = (const float*)d_in[0];
    const float* Wih = (const float*)d_in[1];
    const float* Whh = (const float*)d_in[2];
    const float* bih = (const float*)d_in[3];
    const float* bhh = (const float*)d_in[4];
    const float* Wfc = (const float*)d_in[5];
    const float* bfc = (const float*)d_in[6];

    float* out_newin = (float*)d_out;                 // [T*B] = 524288
    float* out_pred  = out_newin + Tlen * Bsz;        // [B*(T-1)] = 524032

    rnn_imp_kernel<<<Bsz, 512, 0, stream>>>(x, Wih, Whh, bih, bhh, Wfc, bfc,
                                            out_newin, out_pred);
}